// Round 1
// baseline (718.277 us; speedup 1.0000x reference)
//
#include <hip/hip_runtime.h>

#define B_ 32
#define S_ 512
#define D_ 512
#define H_ 8
#define DK_ 64
#define FF_ 2048

typedef float f32x4 __attribute__((ext_vector_type(4)));
typedef __bf16 bf16x8 __attribute__((ext_vector_type(8)));
typedef __bf16 bf16x4 __attribute__((ext_vector_type(4)));

// ---- async global->LDS, 16B per lane (dest must be wave-uniform base + lane*16) ----
__device__ __forceinline__ void gld_lds16(const void* gptr, void* lptr) {
    auto g = (__attribute__((address_space(1))) void*)(unsigned long long)gptr;
    auto l = (__attribute__((address_space(3))) void*)(unsigned)(unsigned long long)lptr;
    __builtin_amdgcn_global_load_lds(g, l, 16, 0, 0);
}

// ---- x = q+pe (fp32 + bf16), y = qa+pe (bf16) ----
__global__ __launch_bounds__(256) void prep_kernel(
    const float* __restrict__ q, const float* __restrict__ qa,
    const float* __restrict__ pe, float* __restrict__ xf,
    __bf16* __restrict__ xbf, __bf16* __restrict__ ybf)
{
    const int n4 = B_ * S_ * D_ / 4;
    for (int i = blockIdx.x * blockDim.x + threadIdx.x; i < n4;
         i += gridDim.x * blockDim.x) {
        float4 pv = ((const float4*)pe)[i & (S_ * D_ / 4 - 1)];
        float4 qv = ((const float4*)q)[i];
        float4 av = ((const float4*)qa)[i];
        float4 xv = make_float4(qv.x + pv.x, qv.y + pv.y, qv.z + pv.z, qv.w + pv.w);
        ((float4*)xf)[i] = xv;
        bf16x4 xb = {(__bf16)xv.x, (__bf16)xv.y, (__bf16)xv.z, (__bf16)xv.w};
        ((bf16x4*)xbf)[i] = xb;
        bf16x4 yb = {(__bf16)(av.x + pv.x), (__bf16)(av.y + pv.y),
                     (__bf16)(av.z + pv.z), (__bf16)(av.w + pv.w)};
        ((bf16x4*)ybf)[i] = yb;
    }
}

// ---- fp32 [R][C] -> bf16 [C][R] (weights to B^T layout) ----
__global__ __launch_bounds__(256) void transpose_cvt(
    const float* __restrict__ in, __bf16* __restrict__ out, int R, int C)
{
    __shared__ float tile[32][33];
    const int tc = blockIdx.x * 32, tr = blockIdx.y * 32;
    const int lx = threadIdx.x & 31, ly = threadIdx.x >> 5;
    #pragma unroll
    for (int yy = ly; yy < 32; yy += 8)
        tile[yy][lx] = in[(long)(tr + yy) * C + tc + lx];
    __syncthreads();
    #pragma unroll
    for (int yy = ly; yy < 32; yy += 8)
        out[(long)(tc + yy) * R + tr + lx] = (__bf16)tile[lx][yy];
}

// ---- V [B,S,H,DK] -> Vt [B,H,DK,S] ----
__global__ __launch_bounds__(256) void vtrans_kernel(
    const __bf16* __restrict__ V, __bf16* __restrict__ Vt)
{
    __shared__ __bf16 tile[64][72];
    const int sb = blockIdx.x, h = blockIdx.y, b = blockIdx.z;
    const int t = threadIdx.x;
    #pragma unroll
    for (int it = 0; it < 16; ++it) {
        int idx = it * 256 + t;
        int rr = idx >> 6, cc = idx & 63;
        tile[cc][rr] = V[((long)(b * S_ + sb * 64 + rr)) * D_ + h * DK_ + cc];
    }
    __syncthreads();
    #pragma unroll
    for (int it = 0; it < 16; ++it) {
        int idx = it * 256 + t;
        int dd = idx >> 6, so = idx & 63;
        Vt[((long)(b * H_ + h) * DK_ + dd) * S_ + sb * 64 + so] = tile[dd][so];
    }
}

// ---- GEMM: C[M,N] = A[M,K](bf16) @ Bt[N,K](bf16)^T + bias; m97-structure 128x128 ----
// MODE 0: bf16 out (+optional RELU). MODE 1: fp32 out = acc + bias + res.
template <int RELU, int MODE>
__global__ __launch_bounds__(256) void gemm_kernel(
    const __bf16* __restrict__ A, const __bf16* __restrict__ Bt,
    const float* __restrict__ bias, const float* __restrict__ res,
    void* __restrict__ outv, int M, int N, int K)
{
    __shared__ __bf16 As[128 * 32];
    __shared__ __bf16 Bs[128 * 32];
    const int t = threadIdx.x;
    const int lane = t & 63;
    const int wv = t >> 6, wr = wv >> 1, wc = wv & 1;
    const int lr = lane & 15, lk = lane >> 4;
    const int m0 = blockIdx.y * 128, n0 = blockIdx.x * 128;

    const int srow = t >> 2, scol = (t & 3) * 8;
    const __bf16* gA = A + (long)(m0 + srow) * K + scol;
    const __bf16* gB = Bt + (long)(n0 + srow) * K + scol;
    char* ldsA = (char*)As + t * 16;
    char* ldsB = (char*)Bs + t * 16;
    const long rstep = (long)64 * K;

    f32x4 acc[4][4] = {};
    for (int k0 = 0; k0 < K; k0 += 32) {
        gld_lds16(gA + k0, ldsA);
        gld_lds16(gA + k0 + rstep, ldsA + 4096);
        gld_lds16(gB + k0, ldsB);
        gld_lds16(gB + k0 + rstep, ldsB + 4096);
        __syncthreads();
        bf16x8 af[4], bfr[4];
        #pragma unroll
        for (int i = 0; i < 4; ++i)
            af[i] = *(const bf16x8*)&As[(wr * 64 + i * 16 + lr) * 32 + lk * 8];
        #pragma unroll
        for (int j = 0; j < 4; ++j)
            bfr[j] = *(const bf16x8*)&Bs[(wc * 64 + j * 16 + lr) * 32 + lk * 8];
        #pragma unroll
        for (int i = 0; i < 4; ++i)
            #pragma unroll
            for (int j = 0; j < 4; ++j)
                acc[i][j] = __builtin_amdgcn_mfma_f32_16x16x32_bf16(
                    af[i], bfr[j], acc[i][j], 0, 0, 0);
        __syncthreads();
    }

    #pragma unroll
    for (int i = 0; i < 4; ++i) {
        #pragma unroll
        for (int j = 0; j < 4; ++j) {
            const int n = n0 + wc * 64 + j * 16 + lr;
            const float bv = bias[n];
            #pragma unroll
            for (int r = 0; r < 4; ++r) {
                const int m = m0 + wr * 64 + i * 16 + lk * 4 + r;
                float v = acc[i][j][r] + bv;
                if (RELU) v = v > 0.f ? v : 0.f;
                const long off = (long)m * N + n;
                if (MODE == 0) ((__bf16*)outv)[off] = (__bf16)v;
                else           ((float*)outv)[off] = v + res[off];
            }
        }
    }
}

// ---- flash attention, strict-causal, per-row forget_rate scaling ----
// Q==K: [B,S,H,DK] bf16. Vt: [B,H,DK,S] bf16. Out: [B,S,D] bf16.
__global__ __launch_bounds__(256) void attn_kernel(
    const __bf16* __restrict__ Q, const __bf16* __restrict__ Vt,
    const float* __restrict__ fr, __bf16* __restrict__ Out)
{
    __shared__ __bf16 Plds[4][16 * 32];
    const int t = threadIdx.x;
    const int lane = t & 63, wv = t >> 6;
    const int lr = lane & 15, lk = lane >> 4;
    const int qb = blockIdx.x, h = blockIdx.y, b = blockIdx.z;
    const int qbase = qb * 64 + wv * 16;

    const __bf16* qptr = Q + (long)(b * S_ + qbase + lr) * D_ + h * DK_ + lk * 8;
    const bf16x8 qf0 = *(const bf16x8*)qptr;
    const bf16x8 qf1 = *(const bf16x8*)(qptr + 32);

    float frv[4], mrun[4], lrun[4];
    #pragma unroll
    for (int r = 0; r < 4; ++r) {
        frv[r] = fr[b * S_ + qbase + lk * 4 + r] * 0.125f;  // fold 1/sqrt(64)
        mrun[r] = -1e30f;
        lrun[r] = 0.f;
    }
    f32x4 o[4] = {};

    const __bf16* kbase = Q + (long)b * S_ * D_ + h * DK_;
    const __bf16* vbase = Vt + (long)(b * H_ + h) * DK_ * S_;
    __bf16* pl = &Plds[wv][0];

    for (int ks = 0; ks < qbase + 16; ks += 32) {
        f32x4 sa[2] = {};
        #pragma unroll
        for (int j = 0; j < 2; ++j) {
            const __bf16* kp = kbase + (long)(ks + j * 16 + lr) * D_ + lk * 8;
            bf16x8 kf0 = *(const bf16x8*)kp;
            bf16x8 kf1 = *(const bf16x8*)(kp + 32);
            sa[j] = __builtin_amdgcn_mfma_f32_16x16x32_bf16(qf0, kf0, sa[j], 0, 0, 0);
            sa[j] = __builtin_amdgcn_mfma_f32_16x16x32_bf16(qf1, kf1, sa[j], 0, 0, 0);
        }
        #pragma unroll
        for (int r = 0; r < 4; ++r) {
            const int qrow = qbase + lk * 4 + r;
            const bool a0 = (ks + lr) < qrow;
            const bool a1 = (ks + 16 + lr) < qrow;
            float s0 = a0 ? sa[0][r] * frv[r] : -1e30f;
            float s1 = a1 ? sa[1][r] * frv[r] : -1e30f;
            float mx = fmaxf(s0, s1);
            #pragma unroll
            for (int d = 1; d < 16; d <<= 1) mx = fmaxf(mx, __shfl_xor(mx, d));
            const float mnew = fmaxf(mrun[r], mx);
            const float fac = __expf(mrun[r] - mnew);  // -1e30 - -1e30 = 0 -> 1, safe
            const float p0 = a0 ? __expf(s0 - mnew) : 0.f;
            const float p1 = a1 ? __expf(s1 - mnew) : 0.f;
            float sum = p0 + p1;
            #pragma unroll
            for (int d = 1; d < 16; d <<= 1) sum += __shfl_xor(sum, d);
            lrun[r] = lrun[r] * fac + sum;
            mrun[r] = mnew;
            #pragma unroll
            for (int dt = 0; dt < 4; ++dt) o[dt][r] *= fac;
            pl[(lk * 4 + r) * 32 + lr]      = (__bf16)p0;
            pl[(lk * 4 + r) * 32 + 16 + lr] = (__bf16)p1;
        }
        // C-layout -> A-layout via wave-private LDS (compiler orders ds ops)
        const bf16x8 pf = *(const bf16x8*)&pl[lr * 32 + lk * 8];
        #pragma unroll
        for (int dt = 0; dt < 4; ++dt) {
            const __bf16* vp = vbase + (long)(dt * 16 + lr) * S_ + ks + lk * 8;
            bf16x8 vf = *(const bf16x8*)vp;
            o[dt] = __builtin_amdgcn_mfma_f32_16x16x32_bf16(pf, vf, o[dt], 0, 0, 0);
        }
    }

    #pragma unroll
    for (int r = 0; r < 4; ++r) {
        const int qrow = qbase + lk * 4 + r;
        const float inv = lrun[r] > 0.f ? 1.f / lrun[r] : 0.f;  // row 0 -> zeros
        #pragma unroll
        for (int dt = 0; dt < 4; ++dt)
            Out[(long)(b * S_ + qrow) * D_ + h * DK_ + dt * 16 + lr] =
                (__bf16)(o[dt][r] * inv);
    }
}

// ---- LayerNorm, wave per row; writes fp32 master + bf16 copy ----
__global__ __launch_bounds__(256) void ln_kernel(
    const float* __restrict__ pre, const float* __restrict__ g,
    const float* __restrict__ be, float* __restrict__ xout,
    __bf16* __restrict__ xbf)
{
    const int lane = threadIdx.x & 63, wv = threadIdx.x >> 6;
    const long row = (long)blockIdx.x * 4 + wv;
    const float* p = pre + row * D_ + lane * 8;
    const float4 a = ((const float4*)p)[0];
    const float4 c = ((const float4*)p)[1];
    float s  = a.x + a.y + a.z + a.w + c.x + c.y + c.z + c.w;
    float ss = a.x * a.x + a.y * a.y + a.z * a.z + a.w * a.w +
               c.x * c.x + c.y * c.y + c.z * c.z + c.w * c.w;
    #pragma unroll
    for (int d = 1; d < 64; d <<= 1) {
        s  += __shfl_xor(s, d);
        ss += __shfl_xor(ss, d);
    }
    const float mean = s * (1.f / 512.f);
    const float rstd = rsqrtf(ss * (1.f / 512.f) - mean * mean + 1e-5f);
    const float4 ga = ((const float4*)(g + lane * 8))[0];
    const float4 gc = ((const float4*)(g + lane * 8))[1];
    const float4 ba = ((const float4*)(be + lane * 8))[0];
    const float4 bc = ((const float4*)(be + lane * 8))[1];
    const float o0 = (a.x - mean) * rstd * ga.x + ba.x;
    const float o1 = (a.y - mean) * rstd * ga.y + ba.y;
    const float o2 = (a.z - mean) * rstd * ga.z + ba.z;
    const float o3 = (a.w - mean) * rstd * ga.w + ba.w;
    const float o4 = (c.x - mean) * rstd * gc.x + bc.x;
    const float o5 = (c.y - mean) * rstd * gc.y + bc.y;
    const float o6 = (c.z - mean) * rstd * gc.z + bc.z;
    const float o7 = (c.w - mean) * rstd * gc.w + bc.w;
    float* xo = xout + row * D_ + lane * 8;
    ((float4*)xo)[0] = make_float4(o0, o1, o2, o3);
    ((float4*)xo)[1] = make_float4(o4, o5, o6, o7);
    bf16x8 xb = {(__bf16)o0, (__bf16)o1, (__bf16)o2, (__bf16)o3,
                 (__bf16)o4, (__bf16)o5, (__bf16)o6, (__bf16)o7};
    *(bf16x8*)(xbf + row * D_ + lane * 8) = xb;
}

extern "C" void kernel_launch(void* const* d_in, const int* in_sizes, int n_in,
                              void* d_out, int out_size, void* d_ws, size_t ws_size,
                              hipStream_t stream) {
    const float* q_embed = (const float*)d_in[0];
    const float* qa_embed = (const float*)d_in[1];
    const float* fr  = (const float*)d_in[2];
    const float* pe  = (const float*)d_in[3];
    const float* Wk  = (const float*)d_in[4];
    const float* bk  = (const float*)d_in[5];
    const float* Wv  = (const float*)d_in[6];
    const float* bv  = (const float*)d_in[7];
    const float* Wo  = (const float*)d_in[8];
    const float* bo  = (const float*)d_in[9];
    const float* g1  = (const float*)d_in[10];
    const float* be1 = (const float*)d_in[11];
    const float* W1  = (const float*)d_in[12];
    const float* bf1 = (const float*)d_in[13];
    const float* W2  = (const float*)d_in[14];
    const float* bf2 = (const float*)d_in[15];
    const float* g2  = (const float*)d_in[16];
    const float* be2 = (const float*)d_in[17];

    // workspace layout (~174 MB)
    char* ws = (char*)d_ws;
    float*  xf    = (float*)(ws + 0);            // 32 MB fp32 residual master
    __bf16* xbf   = (__bf16*)(ws + 33554432);    // 16 MB
    __bf16* ybf   = (__bf16*)(ws + 50331648);    // 16 MB (persists both blocks)
    __bf16* pool  = (__bf16*)(ws + 67108864);    // 64 MB: k/v/vt/attn OR f1
    float*  preln = (float*)(ws + 134217728);    // 32 MB
    __bf16* wts   = (__bf16*)(ws + 167772160);   // 11 MB bf16 transposed weights

    __bf16* kbuf  = pool;
    __bf16* vbuf  = pool + 8388608;
    __bf16* vtbuf = pool + 2 * 8388608;
    __bf16* abuf  = pool + 3 * 8388608;
    __bf16* f1buf = pool;  // 64 MB, aliases k/v/vt/attn (all dead by FFN1)

    __bf16* wkt = wts;
    __bf16* wvt = wts + 524288;
    __bf16* wot = wts + 1048576;
    __bf16* w1t = wts + 1572864;
    __bf16* w2t = wts + 3670016;

    for (int i = 0; i < 2; ++i) {
        transpose_cvt<<<dim3(16, 16), 256, 0, stream>>>(Wk + i * 262144, wkt + i * 262144, 512, 512);
        transpose_cvt<<<dim3(16, 16), 256, 0, stream>>>(Wv + i * 262144, wvt + i * 262144, 512, 512);
        transpose_cvt<<<dim3(16, 16), 256, 0, stream>>>(Wo + i * 262144, wot + i * 262144, 512, 512);
        transpose_cvt<<<dim3(64, 16), 256, 0, stream>>>(W1 + i * 1048576, w1t + i * 1048576, 512, 2048);
        transpose_cvt<<<dim3(16, 64), 256, 0, stream>>>(W2 + i * 1048576, w2t + i * 1048576, 2048, 512);
    }
    prep_kernel<<<2048, 256, 0, stream>>>(q_embed, qa_embed, pe, xf, xbf, ybf);

    for (int i = 0; i < 2; ++i) {
        gemm_kernel<0, 0><<<dim3(4, 128), 256, 0, stream>>>(
            xbf, wkt + i * 262144, bk + i * 512, nullptr, kbuf, 16384, 512, 512);
        gemm_kernel<0, 0><<<dim3(4, 128), 256, 0, stream>>>(
            ybf, wvt + i * 262144, bv + i * 512, nullptr, vbuf, 16384, 512, 512);
        vtrans_kernel<<<dim3(8, 8, 32), 256, 0, stream>>>(vbuf, vtbuf);
        attn_kernel<<<dim3(8, 8, 32), 256, 0, stream>>>(kbuf, vtbuf, fr, abuf);
        gemm_kernel<0, 1><<<dim3(4, 128), 256, 0, stream>>>(
            abuf, wot + i * 262144, bo + i * 512, xf, preln, 16384, 512, 512);
        ln_kernel<<<4096, 256, 0, stream>>>(preln, g1 + i * 512, be1 + i * 512, xf, xbf);
        gemm_kernel<1, 0><<<dim3(16, 128), 256, 0, stream>>>(
            xbf, w1t + i * 1048576, bf1 + i * 2048, nullptr, f1buf, 16384, 2048, 512);
        gemm_kernel<0, 1><<<dim3(4, 128), 256, 0, stream>>>(
            f1buf, w2t + i * 1048576, bf2 + i * 512, xf, preln, 16384, 512, 2048);
        float* xdst = (i == 1) ? (float*)d_out : xf;
        ln_kernel<<<4096, 256, 0, stream>>>(preln, g2 + i * 512, be2 + i * 512, xdst, xbf);
    }
}